// Round 2
// baseline (82.309 us; speedup 1.0000x reference)
//
#include <hip/hip_runtime.h>
#include <cstdint>

// Problem constants (from reference)
#define B 64
#define P 5000
#define G 300
#define C 20
#define SCALE_F 512.0f
#define IOU_TH 0.5f
#define NSPLIT 16                             // pred chunks per image
#define PCHUNK ((P + NSPLIT - 1) / NSPLIT)    // 313 (last chunk short: guard with pend)
#define NTA 256                               // 4-wave blocks -> 4 blocks/CU resident
#define SPT ((PCHUNK + NTA - 1) / NTA)        // 2 slots per thread
#define SENT 0x7FFFFFFF

// Match numpy float32 semantics exactly: no FMA contraction (hipcc defaults
// to contract=fast). Division stays IEEE (no fast-math).
#pragma clang fp contract(off)

// ---------------------------------------------------------------------------
// Kernel A: grid (NSPLIT, B) = 1024 blocks x 256 threads. launch_bounds
// (256,4) => 4 waves/EU = 4 blocks/CU = ALL 1024 blocks co-resident, double
// the round-1 occupancy (sync-phase stalls overlap across 4 blocks now).
// Round-2 structural changes vs round 1:
//  * out_stats score/cls/corr=0 are written in the COALESCED histogram pass
//    (p-order, 12B-stride wave-contiguous stores), not the class-sorted match
//    pass whose scattered 12B stores hit ~64 cache lines per instruction.
//    The match pass now performs no global stores at all.
//  * pred class is kept in registers across the scatter pass (one fewer
//    global read pass); all remaining pred loads are float2 (24B stride is
//    8B-aligned), halving VMEM instruction count.
// Invariants carried over: stable class-sort of targets (preserves argmax
// first-occurrence tie-break); bucket-restricted strict-> argmax == reference
// argmax; "first eligible claimant (lowest p) per target wins" == the scan.
// ---------------------------------------------------------------------------
__global__ __launch_bounds__(NTA, 4) void match_kernel(
    const float* __restrict__ preds,      // [B,P,6]
    const float* __restrict__ labels,     // [B,G,5]
    int* __restrict__ blockfp,            // [B,NSPLIT,G]
    float* __restrict__ out_stats,        // [B,P,3]
    float* __restrict__ out_tcls)         // [B,G]
{
    const int s = blockIdx.x;
    const int b = blockIdx.y;
    const int tid = threadIdx.x;

    __shared__ float4 sb[G];              // class-sorted scaled target boxes
    __shared__ float  sa[G];              // areas
    __shared__ short  ssi[G];             // sorted pos -> original target idx
    __shared__ short  cls_s[G];           // target class (original order)
    __shared__ int    so[C + 1];          // target bucket offsets
    __shared__ int    cnt[C];
    __shared__ int    pcnt[C];            // pred histogram -> running offset
    __shared__ int    firstp[G];          // chunk-local lowest claimant
    __shared__ unsigned short psorted[PCHUNK]; // slot -> global pred idx

    const float* lab = labels + (size_t)b * G * 5;
    const float* prd = preds + (size_t)b * P * 6;
    const int pbase = s * PCHUNK;
    const int pend = (pbase + PCHUNK < P) ? pbase + PCHUNK : P;
    const int npred = pend - pbase;

    // ---- phase 1: init + target classes (+ out_tcls from value in hand) ----
    if (tid < C) { cnt[tid] = 0; pcnt[tid] = 0; }
    for (int t = tid; t < G; t += NTA) {
        float cf = lab[t * 5 + 4];
        cls_s[t] = (short)(int)cf;
        firstp[t] = SENT;
        if (s == 0) out_tcls[(size_t)b * G + t] = cf;
    }
    __syncthreads();

    // ---- phase 2: histograms + coalesced dense stats store ----
    for (int t = tid; t < G; t += NTA) atomicAdd(&cnt[cls_s[t]], 1);
    int myc[SPT];                          // pred class cached for scatter pass
    #pragma unroll
    for (int k = 0; k < SPT; ++k) {
        myc[k] = -1;
        int p = pbase + k * NTA + tid;
        if (p < pend) {
            // (score, cls) as one 8B load; p-order => coalesced
            float2 sc = *reinterpret_cast<const float2*>(prd + (size_t)p * 6 + 4);
            int c = (int)sc.y;
            myc[k] = c;
            atomicAdd(&pcnt[c], 1);
            size_t ip3 = ((size_t)b * P + p) * 3;
            out_stats[ip3 + 0] = 0.0f;     // winners flipped to 1.0 by resolve
            out_stats[ip3 + 1] = sc.x;
            out_stats[ip3 + 2] = sc.y;
        }
    }
    __syncthreads();

    // ---- phase 3: exclusive scans (two serial threads, different waves) ----
    if (tid == 0) {
        int a = 0;
        for (int c = 0; c < C; ++c) { so[c] = a; a += cnt[c]; }
        so[C] = a;
    }
    if (tid == 64) {
        int a = 0;
        for (int c = 0; c < C; ++c) { int v = pcnt[c]; pcnt[c] = a; a += v; }
    }
    __syncthreads();

    // ---- phase 4: stable target scatter + unstable pred scatter ----
    for (int t = tid; t < G; t += NTA) {
        short c = cls_s[t];
        int rank = 0;
        for (int u = 0; u < t; ++u) rank += (cls_s[u] == c) ? 1 : 0;
        int pos = so[c] + rank;
        float x1 = lab[t * 5 + 0] * SCALE_F;   // *512 exact (pow2)
        float y1 = lab[t * 5 + 1] * SCALE_F;
        float x2 = lab[t * 5 + 2] * SCALE_F;
        float y2 = lab[t * 5 + 3] * SCALE_F;
        sb[pos] = make_float4(x1, y1, x2, y2);
        sa[pos] = (x2 - x1) * (y2 - y1);
        ssi[pos] = (short)t;
    }
    #pragma unroll
    for (int k = 0; k < SPT; ++k) {
        int p = pbase + k * NTA + tid;
        if (p < pend) {
            int pos = atomicAdd(&pcnt[myc[k]], 1);   // class from registers
            psorted[pos] = (unsigned short)p;
        }
    }
    __syncthreads();

    // ---- phase 5: match (slot-ordered: lanes mostly same class) ----
    #pragma unroll
    for (int k = 0; k < SPT; ++k) {
        int slot = k * NTA + tid;
        if (slot >= npred) continue;
        int p = psorted[slot];
        const float* pr = prd + (size_t)p * 6;
        float2 q0 = *reinterpret_cast<const float2*>(pr);       // x1,y1
        float2 q1 = *reinterpret_cast<const float2*>(pr + 2);   // x2,y2
        float2 q2 = *reinterpret_cast<const float2*>(pr + 4);   // score,cls
        float px1 = q0.x * SCALE_F;
        float py1 = q0.y * SCALE_F;
        float px2 = q1.x * SCALE_F;
        float py2 = q1.y * SCALE_F;
        float score = q2.x;
        int c = (int)q2.y;
        float parea = (px2 - px1) * (py2 - py1);

        int lo = so[c], hi = so[c + 1];
        float best = -1.0f;
        int bi = -1;
        // bucket preserves original order; strict > keeps FIRST max occurrence
        for (int j = lo; j < hi; ++j) {
            float4 tb = sb[j];                 // few distinct j per wave -> cheap
            float lx = fmaxf(px1, tb.x);
            float ly = fmaxf(py1, tb.y);
            float rx = fminf(px2, tb.z);
            float ry = fminf(py2, tb.w);
            float w = fmaxf(rx - lx, 0.0f);
            float h = fmaxf(ry - ly, 0.0f);
            float inter = w * h;
            float uni = (parea + sa[j]) - inter;   // reference assoc order
            float iou = inter / uni;               // IEEE div
            if (iou > best) { best = iou; bi = ssi[j]; }
        }

        bool eligible = (score > 0.0f) && (hi > lo) && (best > IOU_TH);
        if (eligible) atomicMin(&firstp[bi], p);
    }
    __syncthreads();

    // ---- phase 6: dump chunk-local claims (coalesced) ----
    for (int t = tid; t < G; t += NTA)
        blockfp[((size_t)b * NSPLIT + s) * G + t] = firstp[t];
}

// ---------------------------------------------------------------------------
// Kernel B: tiny sparse resolve. One block per image; thread t min-reduces
// the NSPLIT chunk-local claims for target t; if a winner exists, that pred
// gets corr=1.0 (one 4B store; <=300 per image). lf[t]=p implies p claimed t
// (p claims only its own argmax), so no index array is needed. A pred wins at
// most one target, so the sparse stores never collide. Kernel boundary
// guarantees visibility/ordering of kernel A's stores.
// ---------------------------------------------------------------------------
__global__ __launch_bounds__(512) void resolve_kernel(
    const int* __restrict__ blockfp,      // [B,NSPLIT,G]
    float* __restrict__ out_stats)        // [B,P,3]
{
    const int b = blockIdx.x;
    const int t = threadIdx.x;
    if (t >= G) return;

    const int* fp = blockfp + (size_t)b * NSPLIT * G + t;
    int m = fp[0];
    #pragma unroll
    for (int s = 1; s < NSPLIT; ++s) m = min(m, fp[s * G]);

    if (m != SENT)
        out_stats[((size_t)b * P + m) * 3] = 1.0f;
}

extern "C" void kernel_launch(void* const* d_in, const int* in_sizes, int n_in,
                              void* d_out, int out_size, void* d_ws, size_t ws_size,
                              hipStream_t stream) {
    const float* output = (const float*)d_in[0];   // [B,P,6]
    const float* labels = (const float*)d_in[1];   // [B,G,5]

    float* out_stats = (float*)d_out;                       // [B,P,3]
    float* out_tcls  = (float*)d_out + (size_t)B * P * 3;   // [B,G]

    // workspace layout (no init required — kernel A writes every slot)
    int* blockfp = (int*)d_ws;                              // B*NSPLIT*G ints

    dim3 grid(NSPLIT, B);
    match_kernel<<<grid, NTA, 0, stream>>>(output, labels, blockfp,
                                           out_stats, out_tcls);
    resolve_kernel<<<dim3(B), 512, 0, stream>>>(blockfp, out_stats);
}

// Round 3
// 70.305 us; speedup vs baseline: 1.1707x; 1.1707x over previous
//
#include <hip/hip_runtime.h>
#include <cstdint>

// Problem constants (from reference)
#define B 64
#define P 5000
#define G 300
#define C 20
#define SCALE_F 512.0f
#define IOU_TH 0.5f
#define NSPLIT 8                              // pred chunks per image (round-1 geometry: best measured)
#define PCHUNK ((P + NSPLIT - 1) / NSPLIT)    // 625
#define NTA 512
#define SPT ((PCHUNK + NTA - 1) / NTA)        // 2 slots per thread
#define NCHUNK ((G + 63) / 64)                // 5 target chunks of 64
#define SENT 0x7FFFFFFF

// Match numpy float32 semantics exactly: no FMA contraction (hipcc defaults
// to contract=fast). Division stays IEEE (no fast-math).
#pragma clang fp contract(off)

// ---------------------------------------------------------------------------
// Kernel A: grid (NSPLIT, B) = 512 blocks x 512 threads, 2 blocks/CU
// (16 waves/CU) — the round-1 geometry that measured 73.3us. Round-3 keeps
// round-2's unconfounded improvements (coalesced dense stats store in the
// p-ordered phase, float2 pred loads, register-cached class) and replaces
// the O(G^2) stable-rank loop (worst thread ~300 serial LDS reads, per
// block!) with a two-level stable rank:
//   rank(t) = chist_excl[t/64][c]           (same-class count in earlier chunks)
//           + popc(ballot(c)&lanemask_lt)   (same-class earlier lanes in chunk)
// t == tid is identity order, so this reproduces the original-index order
// exactly -> the jnp.argmax first-occurrence tie-break is preserved.
// Invariants carried over: bucket-restricted strict-> argmax == reference
// argmax; "first eligible claimant (lowest p) per target wins" == the scan.
// ---------------------------------------------------------------------------
__global__ __launch_bounds__(NTA, 4) void match_kernel(
    const float* __restrict__ preds,      // [B,P,6]
    const float* __restrict__ labels,     // [B,G,5]
    int* __restrict__ blockfp,            // [B,NSPLIT,G]
    float* __restrict__ out_stats,        // [B,P,3]
    float* __restrict__ out_tcls)         // [B,G]
{
    const int s = blockIdx.x;
    const int b = blockIdx.y;
    const int tid = threadIdx.x;

    __shared__ float4 sb[G];              // class-sorted scaled target boxes
    __shared__ float  sa[G];              // areas
    __shared__ short  ssi[G];             // sorted pos -> original target idx
    __shared__ short  cls_s[G];           // target class (original order)
    __shared__ int    chist[NCHUNK][C];   // per-chunk class counts -> excl offsets
    __shared__ int    cnt[C];             // per-class totals
    __shared__ int    so[C + 1];          // target bucket offsets
    __shared__ int    pcnt[C];            // pred histogram -> running offset
    __shared__ int    firstp[G];          // chunk-local lowest claimant
    __shared__ unsigned short psorted[PCHUNK]; // slot -> global pred idx

    const float* lab = labels + (size_t)b * G * 5;
    const float* prd = preds + (size_t)b * P * 6;
    const int pbase = s * PCHUNK;
    const int pend = (pbase + PCHUNK < P) ? pbase + PCHUNK : P;
    const int npred = pend - pbase;

    // ---- phase 1: init + target classes (+ out_tcls from value in hand) ----
    if (tid < NCHUNK * C) ((int*)chist)[tid] = 0;
    if (tid < C) pcnt[tid] = 0;
    if (tid < G) {                        // NTA=512 >= G: single pass, t==tid
        float cf = lab[tid * 5 + 4];
        cls_s[tid] = (short)(int)cf;
        firstp[tid] = SENT;
        if (s == 0) out_tcls[(size_t)b * G + tid] = cf;
    }
    __syncthreads();

    // ---- phase 2: histograms + coalesced dense stats store ----
    if (tid < G) atomicAdd(&chist[tid >> 6][cls_s[tid]], 1);
    int myc[SPT];                          // pred class cached for scatter pass
    #pragma unroll
    for (int k = 0; k < SPT; ++k) {
        myc[k] = -1;
        int p = pbase + k * NTA + tid;
        if (p < pend) {
            // (score, cls) as one 8B load; p-order => coalesced
            float2 sc = *reinterpret_cast<const float2*>(prd + (size_t)p * 6 + 4);
            int c = (int)sc.y;
            myc[k] = c;
            atomicAdd(&pcnt[c], 1);
            size_t ip3 = ((size_t)b * P + p) * 3;
            out_stats[ip3 + 0] = 0.0f;     // winners flipped to 1.0 by resolve
            out_stats[ip3 + 1] = sc.x;
            out_stats[ip3 + 2] = sc.y;
        }
    }
    __syncthreads();

    // ---- phase 3a: per-class chunk scan (20 parallel) + pred scan (1) ----
    if (tid < C) {                         // wave 0: 20 threads, 5 iters each
        int run = 0;
        #pragma unroll
        for (int w = 0; w < NCHUNK; ++w) {
            int v = chist[w][tid]; chist[w][tid] = run; run += v;
        }
        cnt[tid] = run;
    }
    if (tid == 64) {                       // wave 1: pred-class exclusive scan
        int a = 0;
        for (int c = 0; c < C; ++c) { int v = pcnt[c]; pcnt[c] = a; a += v; }
    }
    __syncthreads();

    // ---- phase 3b: class-base scan ----
    if (tid == 0) {
        int a = 0;
        for (int c = 0; c < C; ++c) { so[c] = a; a += cnt[c]; }
        so[C] = a;
    }
    __syncthreads();

    // ---- phase 4: stable target scatter (ballot rank) + pred scatter ----
    if (tid < NCHUNK * 64) {               // waves 0..4 fully active (ballot!)
        int c = (tid < G) ? (int)cls_s[tid] : -1;
        unsigned long long mymask = 0;
        #pragma unroll
        for (int cc = 0; cc < C; ++cc) {
            unsigned long long m = __ballot(c == cc);
            if (c == cc) mymask = m;
        }
        if (tid < G) {
            int lane = tid & 63;
            int rank = chist[tid >> 6][c]
                     + __popcll(mymask & ((1ull << lane) - 1));
            int pos = so[c] + rank;
            float x1 = lab[tid * 5 + 0] * SCALE_F;   // *512 exact (pow2)
            float y1 = lab[tid * 5 + 1] * SCALE_F;
            float x2 = lab[tid * 5 + 2] * SCALE_F;
            float y2 = lab[tid * 5 + 3] * SCALE_F;
            sb[pos] = make_float4(x1, y1, x2, y2);
            sa[pos] = (x2 - x1) * (y2 - y1);
            ssi[pos] = (short)tid;
        }
    }
    #pragma unroll
    for (int k = 0; k < SPT; ++k) {
        int p = pbase + k * NTA + tid;
        if (p < pend) {
            int pos = atomicAdd(&pcnt[myc[k]], 1);   // class from registers
            psorted[pos] = (unsigned short)p;
        }
    }
    __syncthreads();

    // ---- phase 5: match (slot-ordered: lanes mostly same class) ----
    #pragma unroll
    for (int k = 0; k < SPT; ++k) {
        int slot = k * NTA + tid;
        if (slot >= npred) continue;
        int p = psorted[slot];
        const float* pr = prd + (size_t)p * 6;
        float2 q0 = *reinterpret_cast<const float2*>(pr);       // x1,y1
        float2 q1 = *reinterpret_cast<const float2*>(pr + 2);   // x2,y2
        float2 q2 = *reinterpret_cast<const float2*>(pr + 4);   // score,cls
        float px1 = q0.x * SCALE_F;
        float py1 = q0.y * SCALE_F;
        float px2 = q1.x * SCALE_F;
        float py2 = q1.y * SCALE_F;
        float score = q2.x;
        int c = (int)q2.y;
        float parea = (px2 - px1) * (py2 - py1);

        int lo = so[c], hi = so[c + 1];
        float best = -1.0f;
        int bi = -1;
        // bucket preserves original order; strict > keeps FIRST max occurrence
        for (int j = lo; j < hi; ++j) {
            float4 tb = sb[j];                 // few distinct j per wave -> cheap
            float lx = fmaxf(px1, tb.x);
            float ly = fmaxf(py1, tb.y);
            float rx = fminf(px2, tb.z);
            float ry = fminf(py2, tb.w);
            float w = fmaxf(rx - lx, 0.0f);
            float h = fmaxf(ry - ly, 0.0f);
            float inter = w * h;
            float uni = (parea + sa[j]) - inter;   // reference assoc order
            float iou = inter / uni;               // IEEE div
            if (iou > best) { best = iou; bi = ssi[j]; }
        }

        bool eligible = (score > 0.0f) && (hi > lo) && (best > IOU_TH);
        if (eligible) atomicMin(&firstp[bi], p);
    }
    __syncthreads();

    // ---- phase 6: dump chunk-local claims (coalesced) ----
    if (tid < G)
        blockfp[((size_t)b * NSPLIT + s) * G + tid] = firstp[tid];
}

// ---------------------------------------------------------------------------
// Kernel B: tiny sparse resolve. One block per image; thread t min-reduces
// the NSPLIT chunk-local claims for target t; if a winner exists, that pred
// gets corr=1.0 (one 4B store; <=300 per image). lf[t]=p implies p claimed t
// (p claims only its own argmax), so no index array is needed. A pred wins at
// most one target, so the sparse stores never collide. Kernel boundary
// guarantees visibility/ordering of kernel A's stores.
// ---------------------------------------------------------------------------
__global__ __launch_bounds__(512) void resolve_kernel(
    const int* __restrict__ blockfp,      // [B,NSPLIT,G]
    float* __restrict__ out_stats)        // [B,P,3]
{
    const int b = blockIdx.x;
    const int t = threadIdx.x;
    if (t >= G) return;

    const int* fp = blockfp + (size_t)b * NSPLIT * G + t;
    int m = fp[0];
    #pragma unroll
    for (int s = 1; s < NSPLIT; ++s) m = min(m, fp[s * G]);

    if (m != SENT)
        out_stats[((size_t)b * P + m) * 3] = 1.0f;
}

extern "C" void kernel_launch(void* const* d_in, const int* in_sizes, int n_in,
                              void* d_out, int out_size, void* d_ws, size_t ws_size,
                              hipStream_t stream) {
    const float* output = (const float*)d_in[0];   // [B,P,6]
    const float* labels = (const float*)d_in[1];   // [B,G,5]

    float* out_stats = (float*)d_out;                       // [B,P,3]
    float* out_tcls  = (float*)d_out + (size_t)B * P * 3;   // [B,G]

    // workspace layout (no init required — kernel A writes every slot)
    int* blockfp = (int*)d_ws;                              // B*NSPLIT*G ints

    dim3 grid(NSPLIT, B);
    match_kernel<<<grid, NTA, 0, stream>>>(output, labels, blockfp,
                                           out_stats, out_tcls);
    resolve_kernel<<<dim3(B), 512, 0, stream>>>(blockfp, out_stats);
}